// Round 11
// baseline (108.422 us; speedup 1.0000x reference)
//
#include <hip/hip_runtime.h>
#include <hip/hip_bf16.h>

#define S_LEN 2048
#define BH_TOTAL 64
#define D_DIM 64
#define NT 32          // S_LEN / 64 kv tiles

typedef float f32x4 __attribute__((ext_vector_type(4)));
typedef float f32x16 __attribute__((ext_vector_type(16)));
typedef __bf16 bf16x8 __attribute__((ext_vector_type(8)));
typedef unsigned short u16x8 __attribute__((ext_vector_type(8)));
typedef unsigned int u32;
typedef u32 u32x2 __attribute__((ext_vector_type(2)));
typedef u32 u32x4 __attribute__((ext_vector_type(4)));

union BF8 { u32x4 w; u16x8 u; bf16x8 b; };

#if __has_builtin(__builtin_amdgcn_exp2f)
#define EX2(x) __builtin_amdgcn_exp2f(x)
#else
#define EX2(x) exp2f(x)
#endif

__device__ __forceinline__ unsigned short f2b(float f) {
  __bf16 h = (__bf16)f;
  return __builtin_bit_cast(unsigned short, h);
}
__device__ __forceinline__ u32 pk2(float a, float b) {
  return (u32)f2b(a) | ((u32)f2b(b) << 16);
}

__device__ __forceinline__ u32x2 pl32(u32 x, u32 y) {
#if __has_builtin(__builtin_amdgcn_permlane32_swap)
  return __builtin_amdgcn_permlane32_swap(x, y, false, false);
#else
  u32 xs = (u32)__shfl_xor((int)x, 32);
  u32 ys = (u32)__shfl_xor((int)y, 32);
  int hi = (int)(threadIdx.x & 32);
  u32x2 r;
  r.x = hi ? ys : x;
  r.y = hi ? y : xs;
  return r;
#endif
}

__device__ __forceinline__ void gload16(const unsigned short* g, unsigned short* l) {
  __builtin_amdgcn_global_load_lds(
      (const __attribute__((address_space(1))) unsigned int*)g,
      (__attribute__((address_space(3))) unsigned int*)l, 16, 0, 0);
}

// ---------------- merged pre-pass: K->bf16 and V->bf16-transposed ----------------
__global__ __launch_bounds__(256)
void prep(const float* __restrict__ K, const float* __restrict__ V,
          unsigned short* __restrict__ Kb, unsigned short* __restrict__ Vt) {
  __shared__ unsigned short T[64][72];
  if (blockIdx.x < 4096) {
    int i = blockIdx.x * 256 + threadIdx.x;
    const f32x4* src = (const f32x4*)K;
    f32x4 a = src[2 * i], b = src[2 * i + 1];
    u16x8 o;
    #pragma unroll
    for (int j = 0; j < 4; ++j) { o[j] = f2b(a[j]); o[j + 4] = f2b(b[j]); }
    ((u16x8*)Kb)[i] = o;
  } else {
    int bid = blockIdx.x - 4096;
    int bh = bid >> 5, t5 = bid & 31;
    int s0 = t5 * 64;
    int tid = threadIdx.x;
    {
      int s = tid >> 2, d0 = (tid & 3) * 16;
      const float* src = V + ((size_t)bh * S_LEN + s0 + s) * D_DIM + d0;
      #pragma unroll
      for (int j = 0; j < 16; j += 4) {
        f32x4 x = *(const f32x4*)(src + j);
        #pragma unroll
        for (int q2 = 0; q2 < 4; ++q2) T[d0 + j + q2][s] = f2b(x[q2]);
      }
    }
    __syncthreads();
    {
      int d = tid >> 2, c0 = (tid & 3) * 16;
      unsigned short* dst = Vt + ((size_t)bh * D_DIM + d) * S_LEN + s0 + c0;
      u16x8 o;
      #pragma unroll
      for (int q2 = 0; q2 < 8; ++q2) o[q2] = T[d][c0 + q2];
      *(u16x8*)dst = o;
      #pragma unroll
      for (int q2 = 0; q2 < 8; ++q2) o[q2] = T[d][c0 + 8 + q2];
      *(u16x8*)(dst + 8) = o;
    }
  }
}

// ---- exp2 + pack + permlane: s-tile (f32x16) -> two P B-frags ----
__device__ __forceinline__ void exppack(const f32x16 sv, float& ls, BF8& pA, BF8& pB) {
  u32 wlo[4], whi[4];
  #pragma unroll
  for (int b2 = 0; b2 < 4; ++b2) {
    float e0 = EX2(sv[4 * b2 + 0]), e1 = EX2(sv[4 * b2 + 1]);
    float e2 = EX2(sv[4 * b2 + 2]), e3 = EX2(sv[4 * b2 + 3]);
    ls += (e0 + e1) + (e2 + e3);
    wlo[b2] = pk2(e0, e1);
    whi[b2] = pk2(e2, e3);
  }
  u32x2 rlo = pl32(wlo[0], wlo[1]);
  u32x2 rhi = pl32(whi[0], whi[1]);
  pA.w[0] = rlo.x; pA.w[1] = rhi.x; pA.w[2] = rlo.y; pA.w[3] = rhi.y;
  rlo = pl32(wlo[2], wlo[3]);
  rhi = pl32(whi[2], whi[3]);
  pB.w[0] = rlo.x; pB.w[1] = rhi.x; pB.w[2] = rlo.y; pB.w[3] = rhi.y;
}

#define MFMA32(A, B, C) __builtin_amdgcn_mfma_f32_32x32x16_bf16((A), (B), (C), 0, 0, 0)

// ---------------- main attention: 4 waves x 64q (2 q-subtiles), shared K/V frag reads ----------------
// LDS phys layout: phys_byte(row, colbyte) = row*128 + (colbyte ^ ((row&7)<<4))
__global__ __launch_bounds__(256, 2)
void attn_fwd(const float* __restrict__ Q, const unsigned short* __restrict__ Kb,
              const unsigned short* __restrict__ Vt, float* __restrict__ O) {
  const int wg = blockIdx.x;
  const int id = (wg & 7) * 64 + (wg >> 3);   // bijective XCD swizzle (512 % 8 == 0)
  const int qt = id & 7;                      // 8 q-tiles of 256 rows
  const int bh = id >> 3;

  const int tid = threadIdx.x;
  const int w = tid >> 6;      // 0..3
  const int ln = tid & 63;
  const int l31 = ln & 31;
  const int h = ln >> 5;

  __shared__ __align__(16) unsigned short Ks[2][4096];   // K [kv 64][d 64], swizzled, dbuf
  __shared__ __align__(16) unsigned short Vs[2][4096];   // V^T [d 64][kv 64], swizzled, dbuf

  const size_t hbase = (size_t)bh * S_LEN * D_DIM;
  const unsigned short* Kh = Kb + hbase;
  const unsigned short* Vh = Vt + hbase;

  const int q0 = qt * 256 + w * 64;   // wave owns 64 q rows: [q0, q0+64)

  // ---- Q B-fragments for both q-subtiles, scale*log2e folded ----
  BF8 qf0[4], qf1[4];
  {
    const float sc = 0.125f * 1.44269504088896f;
    #pragma unroll
    for (int qs = 0; qs < 2; ++qs) {
      const float* qp = Q + hbase + (size_t)(q0 + qs * 32 + l31) * D_DIM + h * 8;
      #pragma unroll
      for (int f = 0; f < 4; ++f) {
        f32x4 a = *(const f32x4*)(qp + f * 16);
        f32x4 b = *(const f32x4*)(qp + f * 16 + 4);
        BF8& dst = qs ? qf1[f] : qf0[f];
        #pragma unroll
        for (int j = 0; j < 4; ++j) {
          dst.u[j]     = f2b(a[j] * sc);
          dst.u[j + 4] = f2b(b[j] * sc);
        }
      }
    }
  }

  // ---- staging sources (inverse-swizzled); wave w covers rows [w*16, w*16+16) ----
  const int srow = ln >> 3;
  const int scol = ((ln & 7) ^ srow) * 8;
  const unsigned short* ks0 = Kh + (size_t)(w * 16 + srow) * D_DIM + scol;
  const unsigned short* vs0 = Vh + (size_t)(w * 16 + srow) * S_LEN + scol;

  // ---- fragment read offsets ----
  const int swz = (ln & 7) << 4;
  const int rb = l31 * 128;
  int cx[4];
  #pragma unroll
  for (int m = 0; m < 4; ++m) cx[m] = (m * 32 + h * 16) ^ swz;

  f32x16 oa00, oa01, oa10, oa11;   // [q-sub][d-sub]
  #pragma unroll
  for (int j = 0; j < 16; ++j) { oa00[j] = 0.f; oa01[j] = 0.f; oa10[j] = 0.f; oa11[j] = 0.f; }
  float ls0 = 0.f, ls1 = 0.f;

  // prologue: stage tile 0
  gload16(ks0,             &Ks[0][w * 1024]);
  gload16(ks0 + 512,       &Ks[0][w * 1024 + 512]);
  gload16(vs0,             &Vs[0][w * 1024]);
  gload16(vs0 + 8 * S_LEN, &Vs[0][w * 1024 + 512]);
  __syncthreads();

  for (int t = 0; t < NT; ++t) {
    const int cur = t & 1;
    if (t + 1 < NT) {
      const unsigned short* kp = ks0 + (size_t)(t + 1) * 4096;
      const unsigned short* vp = vs0 + (t + 1) * 64;
      gload16(kp,             &Ks[cur ^ 1][w * 1024]);
      gload16(kp + 512,       &Ks[cur ^ 1][w * 1024 + 512]);
      gload16(vp,             &Vs[cur ^ 1][w * 1024]);
      gload16(vp + 8 * S_LEN, &Vs[cur ^ 1][w * 1024 + 512]);
    }

    const char* KsB = (const char*)&Ks[cur][0];
    const char* VsB = (const char*)&Vs[cur][0];

    // ---- QK: each K frag read once, feeds both q-subtiles (4 indep chains) ----
    f32x16 s00, s01, s10, s11;   // [q-sub][kv-sub]
    #pragma unroll
    for (int j = 0; j < 16; ++j) { s00[j] = 0.f; s01[j] = 0.f; s10[j] = 0.f; s11[j] = 0.f; }
    __builtin_amdgcn_s_setprio(1);
    #pragma unroll
    for (int f = 0; f < 4; ++f) {
      BF8 k0, k1;
      k0.u = *(const u16x8*)(KsB + rb + cx[f]);
      k1.u = *(const u16x8*)(KsB + 4096 + rb + cx[f]);
      s00 = MFMA32(k0.b, qf0[f].b, s00);
      s01 = MFMA32(k1.b, qf0[f].b, s01);
      s10 = MFMA32(k0.b, qf1[f].b, s10);
      s11 = MFMA32(k1.b, qf1[f].b, s11);
    }
    __builtin_amdgcn_s_setprio(0);

    // ---- first V-fragment reads hide under exp/pack VALU ----
    BF8 va, vb;
    va.u = *(const u16x8*)(VsB + rb + cx[0]);
    vb.u = *(const u16x8*)(VsB + 4096 + rb + cx[0]);

    // ---- exp2+pack both q-subtiles -> 8 P^T B-frags ----
    BF8 p00A, p00B, p01A, p01B, p10A, p10B, p11A, p11B;
    exppack(s00, ls0, p00A, p00B);
    exppack(s01, ls0, p01A, p01B);
    exppack(s10, ls1, p10A, p10B);
    exppack(s11, ls1, p11A, p11B);

    // ---- PV: each V frag read once, feeds both q-subtiles ----
    __builtin_amdgcn_s_setprio(1);
    {
      BF8 vc, vd;
      vc.u = *(const u16x8*)(VsB + rb + cx[1]);
      vd.u = *(const u16x8*)(VsB + 4096 + rb + cx[1]);
      oa00 = MFMA32(va.b, p00A.b, oa00);
      oa01 = MFMA32(vb.b, p00A.b, oa01);
      oa10 = MFMA32(va.b, p10A.b, oa10);
      oa11 = MFMA32(vb.b, p10A.b, oa11);
      va.u = *(const u16x8*)(VsB + rb + cx[2]);
      vb.u = *(const u16x8*)(VsB + 4096 + rb + cx[2]);
      oa00 = MFMA32(vc.b, p00B.b, oa00);
      oa01 = MFMA32(vd.b, p00B.b, oa01);
      oa10 = MFMA32(vc.b, p10B.b, oa10);
      oa11 = MFMA32(vd.b, p10B.b, oa11);
      vc.u = *(const u16x8*)(VsB + rb + cx[3]);
      vd.u = *(const u16x8*)(VsB + 4096 + rb + cx[3]);
      oa00 = MFMA32(va.b, p01A.b, oa00);
      oa01 = MFMA32(vb.b, p01A.b, oa01);
      oa10 = MFMA32(va.b, p11A.b, oa10);
      oa11 = MFMA32(vb.b, p11A.b, oa11);
      oa00 = MFMA32(vc.b, p01B.b, oa00);
      oa01 = MFMA32(vd.b, p01B.b, oa01);
      oa10 = MFMA32(vc.b, p11B.b, oa10);
      oa11 = MFMA32(vd.b, p11B.b, oa11);
    }
    __builtin_amdgcn_s_setprio(0);

    __syncthreads();   // drains vmcnt (next tile staged); guards buffer flip
  }

  // ---- epilogue: O[q][d] = O^T[d][q] / l ----
  #pragma unroll
  for (int qs = 0; qs < 2; ++qs) {
    float lsq = qs ? ls1 : ls0;
    float lo2 = __shfl_xor(lsq, 32);
    float inv = 1.0f / (lsq + lo2);
    float* op = O + hbase + (size_t)(q0 + qs * 32 + l31) * D_DIM;
    #pragma unroll
    for (int dt = 0; dt < 2; ++dt) {
      const f32x16 oa = qs ? (dt ? oa11 : oa10) : (dt ? oa01 : oa00);
      #pragma unroll
      for (int b2 = 0; b2 < 4; ++b2) {
        f32x4 vv;
        vv[0] = oa[4 * b2 + 0] * inv;
        vv[1] = oa[4 * b2 + 1] * inv;
        vv[2] = oa[4 * b2 + 2] * inv;
        vv[3] = oa[4 * b2 + 3] * inv;
        *(f32x4*)(op + dt * 32 + b2 * 8 + h * 4) = vv;
      }
    }
  }
}

extern "C" void kernel_launch(void* const* d_in, const int* in_sizes, int n_in,
                              void* d_out, int out_size, void* d_ws, size_t ws_size,
                              hipStream_t stream) {
  const float* q = (const float*)d_in[0];
  const float* k = (const float*)d_in[1];
  const float* v = (const float*)d_in[2];
  float* o = (float*)d_out;
  unsigned short* kb = (unsigned short*)d_ws;
  unsigned short* vt = kb + (size_t)BH_TOTAL * S_LEN * D_DIM;

  prep<<<dim3(4096 + 2048), 256, 0, stream>>>(k, v, kb, vt);
  attn_fwd<<<dim3(512), 256, 0, stream>>>(q, kb, vt, o);
}